// Round 2
// baseline (408.554 us; speedup 1.0000x reference)
//
#include <hip/hip_runtime.h>
#include <cstdint>
#include <cstddef>

// DigitCapsule dynamic routing, fp32.
// x[256,1152,8], W[1152,10,16,8], out v[256,10,16].
// votes(b,i,j,d) = sum_p W[i,j,d,p]*x[b,i,p]  (recomputed, never materialized)
// Logits trick: b_r = votes . (v0+...+v_{r-1})  ->  only vsum[B,J,D] persisted.
constexpr int Bn = 256, In = 1152, Pn = 8, Jn = 10, Dn = 16;
constexpr int GB = 4;  // batch elems per capsA block

// capsA: s[b,j,:] = sum_i c[b,i,j]*vote(b,i,j,:);  v = squash(s)
// Thread layout: d = t&15 (one MFMA-free dot per d), g = t>>4 strides i.
// MODE 0: c = 0.1 (softmax of zero logits), vsum = v
// MODE 1: c from cbuf, vsum += v
// MODE 2: c from cbuf, write final out (fp32)
template <int MODE>
__global__ __launch_bounds__(256) void capsA(
    const float* __restrict__ x, const float* __restrict__ w,
    const float* __restrict__ cbuf, float* __restrict__ vsum,
    float* __restrict__ out)
{
  __shared__ float lds[4 * GB * Dn];  // [wave][b][d]
  const int t  = threadIdx.x;
  const int d  = t & 15, g = t >> 4;  // g in 0..15
  const int j  = blockIdx.y;
  const int b0 = blockIdx.x * GB;

  float sacc[GB] = {0.f, 0.f, 0.f, 0.f};

  for (int i = g; i < In; i += 16) {
    const float* wr = w + ((size_t)i * Jn + j) * (Dn * Pn) + d * Pn;
    const float4 w0 = *(const float4*)wr;
    const float4 w1 = *(const float4*)(wr + 4);
    #pragma unroll
    for (int b = 0; b < GB; ++b) {
      const float* xr = x + ((size_t)(b0 + b) * In + i) * Pn;
      const float4 x0 = *(const float4*)xr;
      const float4 x1 = *(const float4*)(xr + 4);
      float dot = w0.x * x0.x;
      dot = fmaf(w0.y, x0.y, dot); dot = fmaf(w0.z, x0.z, dot);
      dot = fmaf(w0.w, x0.w, dot); dot = fmaf(w1.x, x1.x, dot);
      dot = fmaf(w1.y, x1.y, dot); dot = fmaf(w1.z, x1.z, dot);
      dot = fmaf(w1.w, x1.w, dot);
      const float c = (MODE == 0)
          ? 0.1f
          : cbuf[((size_t)(b0 + b) * Jn + j) * In + i];
      sacc[b] = fmaf(c, dot, sacc[b]);
    }
  }

  // Reduce over g: 4 g's within the wave via shuffles, 4 waves via LDS.
  #pragma unroll
  for (int b = 0; b < GB; ++b) {
    sacc[b] += __shfl_xor(sacc[b], 16, 64);
    sacc[b] += __shfl_xor(sacc[b], 32, 64);
  }
  const int wv = t >> 6, lane = t & 63;
  if (lane < 16) {
    #pragma unroll
    for (int b = 0; b < GB; ++b) lds[(wv * GB + b) * Dn + lane] = sacc[b];
  }
  __syncthreads();

  if (t < GB * Dn) {  // wave 0 only (uniform branch for wave 0)
    const int b = t >> 4, dd = t & 15;
    float s = 0.f;
    #pragma unroll
    for (int w4 = 0; w4 < 4; ++w4) s += lds[(w4 * GB + b) * Dn + dd];
    // squash: need ||s||^2 over the 16 d's (= the 16-lane group of this b)
    float n2 = s * s;
    #pragma unroll
    for (int off = 1; off < 16; off <<= 1) n2 += __shfl_xor(n2, off, 64);
    const float scale = n2 / (1.f + n2) / sqrtf(n2 + 1e-7f);
    const float val = s * scale;
    const size_t o = ((size_t)(b0 + b) * Jn + j) * Dn + dd;
    if (MODE == 2)      out[o]  = val;
    else if (MODE == 0) vsum[o] = val;
    else                vsum[o] += val;
  }
}

// capsB: logits l[b,i,j] = sum_d vote(b,i,j,d)*vsum[b,j,d]; c = softmax_j(l)
// Thread = one (b,i); wave = one b x 64 contiguous i. W staged per-j in LDS.
__global__ __launch_bounds__(256) void capsB(
    const float* __restrict__ x, const float* __restrict__ w,
    float* __restrict__ cbuf, const float* __restrict__ vsum)
{
  __shared__ float wlds[64 * 132];  // 64 i-rows x 128 dwords, stride 132 (33 KB)
  const int t  = threadIdx.x;
  const int il = t & 63, bs = t >> 6;
  const int i0 = blockIdx.x * 64;
  const int b  = blockIdx.y * GB + bs;

  const float* xr = x + ((size_t)b * In + (i0 + il)) * Pn;
  const float4 x0 = *(const float4*)xr;
  const float4 x1 = *(const float4*)(xr + 4);
  const float* vb = vsum + (size_t)b * Jn * Dn;

  float l[Jn];

  for (int j = 0; j < Jn; ++j) {
    __syncthreads();
    // Stage W[i0:i0+64, j, :, :] (64 rows x 512B, global stride 5120B).
    #pragma unroll
    for (int k = 0; k < 8; ++k) {
      const int e   = (t + k * 256) * 4;  // 0..8188
      const int row = e >> 7, col = e & 127;
      const float4 q =
          *(const float4*)(w + ((size_t)(i0 + row) * Jn + j) * 128 + col);
      *(float4*)(&wlds[row * 132 + col]) = q;
    }
    __syncthreads();

    float a = 0.f;
    #pragma unroll
    for (int dd = 0; dd < Dn; ++dd) {
      const float* wr = &wlds[il * 132 + dd * 8];
      const float4 w0 = *(const float4*)wr;
      const float4 w1 = *(const float4*)(wr + 4);
      float dot = w0.x * x0.x;
      dot = fmaf(w0.y, x0.y, dot); dot = fmaf(w0.z, x0.z, dot);
      dot = fmaf(w0.w, x0.w, dot); dot = fmaf(w1.x, x1.x, dot);
      dot = fmaf(w1.y, x1.y, dot); dot = fmaf(w1.z, x1.z, dot);
      dot = fmaf(w1.w, x1.w, dot);
      a = fmaf(dot, vb[j * Dn + dd], a);
    }
    l[j] = a;
  }

  // softmax over j, write c (layout [B,J,I] so capsA reads are i-coalesced)
  float m = l[0];
  #pragma unroll
  for (int j = 1; j < Jn; ++j) m = fmaxf(m, l[j]);
  float ssum = 0.f;
  #pragma unroll
  for (int j = 0; j < Jn; ++j) { l[j] = __expf(l[j] - m); ssum += l[j]; }
  const float inv = 1.f / ssum;
  #pragma unroll
  for (int j = 0; j < Jn; ++j)
    cbuf[((size_t)b * Jn + j) * In + i0 + il] = l[j] * inv;
}

extern "C" void kernel_launch(void* const* d_in, const int* in_sizes, int n_in,
                              void* d_out, int out_size, void* d_ws, size_t ws_size,
                              hipStream_t stream)
{
  const float* x = (const float*)d_in[0];  // [256,1152,8] fp32
  const float* w = (const float*)d_in[1];  // [1152,10,16,8] fp32
  float* cbuf = (float*)d_ws;                       // [B,J,I] coupling coeffs
  float* vsum = cbuf + (size_t)Bn * Jn * In;        // [B,J,D] running v-sum
  float* out  = (float*)d_out;                      // [256,10,16] fp32

  dim3 gA(Bn / GB, Jn), bA(256);
  dim3 gB(In / 64, Bn / GB), bB(256);

  capsA<0><<<gA, bA, 0, stream>>>(x, w, nullptr, vsum, out);  // v0 -> vsum
  capsB<<<gB, bB, 0, stream>>>(x, w, cbuf, vsum);             // c1 = smax(votes.v0)
  capsA<1><<<gA, bA, 0, stream>>>(x, w, cbuf, vsum, out);     // v1, vsum += v1
  capsB<<<gB, bB, 0, stream>>>(x, w, cbuf, vsum);             // c2
  capsA<2><<<gA, bA, 0, stream>>>(x, w, cbuf, vsum, out);     // v2 -> out
}

// Round 3
// 211.175 us; speedup vs baseline: 1.9347x; 1.9347x over previous
//
#include <hip/hip_runtime.h>
#include <cstdint>
#include <cstddef>

// DigitCapsule dynamic routing, fp32, b-per-lane layout.
// x[256,1152,8], W[1152,10,16,8], out v[256,10,16].
// vsum trick: logits at round r = votes . (v0+...+v_{r-1}).
constexpr int Bn = 256, In = 1152, Pn = 8, Jn = 10, Dn = 16;
constexpr int CA = 12, NCH = In / CA;  // capsA i-chunk, 96 chunks

// One-time transpose x[B][I*P] -> xT[I*P][B] so lane=b reads coalesce.
__global__ __launch_bounds__(256) void xpose(const float* __restrict__ x,
                                             float* __restrict__ xT) {
  __shared__ float tile[64][65];
  const int t = threadIdx.x, r = t >> 6, c = t & 63;
  const int ip0 = blockIdx.x * 64, b0 = blockIdx.y * 64;
  #pragma unroll
  for (int k = 0; k < 16; ++k) {
    const int row = k * 4 + r;
    tile[row][c] = x[(size_t)(b0 + row) * (In * Pn) + ip0 + c];
  }
  __syncthreads();
  #pragma unroll
  for (int k = 0; k < 16; ++k) {
    const int row = k * 4 + r;
    xT[(size_t)(ip0 + row) * Bn + b0 + c] = tile[c][row];
  }
}

// capsA: partial s[b,j,d] over an i-chunk. thread=b, block=(chunk, j).
// W addresses are wave-uniform -> SMEM; x/c loads coalesced b32.
// MODE 0: c = 0.1 ; MODE 1: c from cbuf[j][i][b].
template <int MODE>
__global__ __launch_bounds__(256) void capsA(
    const float* __restrict__ xT, const float* __restrict__ w,
    const float* __restrict__ cbuf, float* __restrict__ spart) {
  const int b = threadIdx.x, ch = blockIdx.x, j = blockIdx.y;
  float s[Dn];
  #pragma unroll
  for (int d = 0; d < Dn; ++d) s[d] = 0.f;

  const int i0 = ch * CA;
  for (int ii = 0; ii < CA; ++ii) {
    const int i = i0 + ii;
    const float* xr = xT + (size_t)i * (Pn * Bn) + b;
    float xc[Pn];
    #pragma unroll
    for (int p = 0; p < Pn; ++p) xc[p] = xr[p * Bn];
    float c = 0.1f;
    if (MODE) c = cbuf[((size_t)j * In + i) * Bn + b];
    #pragma unroll
    for (int p = 0; p < Pn; ++p) xc[p] *= c;

    const float* wr = w + ((size_t)i * Jn + j) * (Dn * Pn);
    #pragma unroll
    for (int d = 0; d < Dn; ++d) {
      const float* wd = wr + d * Pn;
      float dot = wd[0] * xc[0];
      dot = fmaf(wd[1], xc[1], dot); dot = fmaf(wd[2], xc[2], dot);
      dot = fmaf(wd[3], xc[3], dot); dot = fmaf(wd[4], xc[4], dot);
      dot = fmaf(wd[5], xc[5], dot); dot = fmaf(wd[6], xc[6], dot);
      dot = fmaf(wd[7], xc[7], dot);
      s[d] += dot;
    }
  }
  float* sp = spart + (((size_t)ch * Jn + j) * Dn) * Bn + b;
  #pragma unroll
  for (int d = 0; d < Dn; ++d) sp[d * Bn] = s[d];
}

// capsF: reduce 96 chunk-partials, squash.
// MODE 0: vsumT = v ; MODE 1: vsumT += v ; MODE 2: out[b][j][d] = v.
template <int MODE>
__global__ __launch_bounds__(256) void capsF(
    const float* __restrict__ spart, float* __restrict__ vsumT,
    float* __restrict__ out) {
  __shared__ float red[4][64][17];
  const int t = threadIdx.x, bl = t & 63, cg = t >> 6;
  const int j = blockIdx.x, b = blockIdx.y * 64 + bl;
  float s[Dn];
  #pragma unroll
  for (int d = 0; d < Dn; ++d) s[d] = 0.f;
  for (int ch = cg; ch < NCH; ch += 4) {
    const float* sp = spart + (((size_t)ch * Jn + j) * Dn) * Bn + b;
    #pragma unroll
    for (int d = 0; d < Dn; ++d) s[d] += sp[d * Bn];
  }
  #pragma unroll
  for (int d = 0; d < Dn; ++d) red[cg][bl][d] = s[d];
  __syncthreads();
  if (t < 64) {
    float v[Dn], n2 = 0.f;
    #pragma unroll
    for (int d = 0; d < Dn; ++d) {
      const float z = red[0][bl][d] + red[1][bl][d] + red[2][bl][d] + red[3][bl][d];
      v[d] = z;
      n2 = fmaf(z, z, n2);
    }
    const float sc = n2 / (1.f + n2) / sqrtf(n2 + 1e-7f);
    if (MODE == 2) {
      float* o = out + ((size_t)b * Jn + j) * Dn;
      #pragma unroll
      for (int d = 0; d < Dn; ++d) o[d] = v[d] * sc;
    } else if (MODE == 1) {
      #pragma unroll
      for (int d = 0; d < Dn; ++d) vsumT[((size_t)j * Dn + d) * Bn + b] += v[d] * sc;
    } else {
      #pragma unroll
      for (int d = 0; d < Dn; ++d) vsumT[((size_t)j * Dn + d) * Bn + b] = v[d] * sc;
    }
  }
}

// capsB: logits l[j] = sum_d vote(b,i,j,d)*vsum[b,j,d]; c = softmax_j -> cbuf[j][i][b].
// thread=b, block=i. No LDS; W wave-uniform (SMEM), vsumT/x/c coalesced.
__global__ __launch_bounds__(256) void capsB(
    const float* __restrict__ xT, const float* __restrict__ w,
    const float* __restrict__ vsumT, float* __restrict__ cbuf) {
  const int b = threadIdx.x, i = blockIdx.x;
  const float* xr = xT + (size_t)i * (Pn * Bn) + b;
  float xv[Pn];
  #pragma unroll
  for (int p = 0; p < Pn; ++p) xv[p] = xr[p * Bn];

  float l[Jn];
  #pragma unroll 2
  for (int j = 0; j < Jn; ++j) {
    const float* wr = w + ((size_t)i * Jn + j) * (Dn * Pn);
    float acc = 0.f;
    #pragma unroll
    for (int d = 0; d < Dn; ++d) {
      const float* wd = wr + d * Pn;
      float dot = wd[0] * xv[0];
      dot = fmaf(wd[1], xv[1], dot); dot = fmaf(wd[2], xv[2], dot);
      dot = fmaf(wd[3], xv[3], dot); dot = fmaf(wd[4], xv[4], dot);
      dot = fmaf(wd[5], xv[5], dot); dot = fmaf(wd[6], xv[6], dot);
      dot = fmaf(wd[7], xv[7], dot);
      acc = fmaf(dot, vsumT[((size_t)j * Dn + d) * Bn + b], acc);
    }
    l[j] = acc;
  }

  float m = l[0];
  #pragma unroll
  for (int j = 1; j < Jn; ++j) m = fmaxf(m, l[j]);
  float ssum = 0.f;
  #pragma unroll
  for (int j = 0; j < Jn; ++j) { l[j] = __expf(l[j] - m); ssum += l[j]; }
  const float inv = 1.f / ssum;
  #pragma unroll
  for (int j = 0; j < Jn; ++j)
    cbuf[((size_t)j * In + i) * Bn + b] = l[j] * inv;
}

extern "C" void kernel_launch(void* const* d_in, const int* in_sizes, int n_in,
                              void* d_out, int out_size, void* d_ws, size_t ws_size,
                              hipStream_t stream) {
  const float* x = (const float*)d_in[0];  // [256,1152,8]
  const float* w = (const float*)d_in[1];  // [1152,10,16,8]
  float* xT    = (float*)d_ws;                      // [I*P][B]   9.44 MB
  float* cbuf  = xT + (size_t)In * Pn * Bn;         // [J][I][B] 11.80 MB
  float* vsumT = cbuf + (size_t)Jn * In * Bn;       // [J][D][B]  0.16 MB
  float* spart = vsumT + (size_t)Jn * Dn * Bn;      // [NCH][J][D][B] 15.73 MB
  float* out = (float*)d_out;                       // [256,10,16]

  xpose<<<dim3((In * Pn) / 64, Bn / 64), 256, 0, stream>>>(x, xT);

  capsA<0><<<dim3(NCH, Jn), 256, 0, stream>>>(xT, w, nullptr, spart);
  capsF<0><<<dim3(Jn, 4), 256, 0, stream>>>(spart, vsumT, out);   // vsum = v0

  capsB<<<In, 256, 0, stream>>>(xT, w, vsumT, cbuf);              // c1
  capsA<1><<<dim3(NCH, Jn), 256, 0, stream>>>(xT, w, cbuf, spart);
  capsF<1><<<dim3(Jn, 4), 256, 0, stream>>>(spart, vsumT, out);   // vsum += v1

  capsB<<<In, 256, 0, stream>>>(xT, w, vsumT, cbuf);              // c2
  capsA<1><<<dim3(NCH, Jn), 256, 0, stream>>>(xT, w, cbuf, spart);
  capsF<2><<<dim3(Jn, 4), 256, 0, stream>>>(spart, vsumT, out);   // out = v2
}